// Round 6
// baseline (56.612 us; speedup 1.0000x reference)
//
#include <hip/hip_runtime.h>
#include <math.h>

#define NQ   11
#define DIM  2048        // 2^11
#define NL   6

typedef float v2f __attribute__((ext_vector_type(2)));   // (re, im) -> v_pk_*_f32

// GF(2)-linear swizzle (R3-proven for all L0/L1/L2/perm patterns @256 threads):
// swz(a^b) = swz(a)^swz(b) -> per-thread base XOR compile-time k-constant.
__host__ __device__ constexpr int swzA(int x) {
    return x ^ ((x >> 6) & 31) ^ ((x & 2) << 3) ^ ((x & 1) << 3);
}

// complex multiply-accumulate: acc + u*a, packed
__device__ __forceinline__ v2f cmadd(v2f u, v2f a, v2f acc) {
    v2f ap; ap.x = -a.y; ap.y = a.x;      // i*a
    acc += u.x * a;                        // v_pk_fma_f32
    acc += u.y * ap;                       // v_pk_fma_f32
    return acc;
}

// ================= kernel 1: all sample-independent work, 1 block ============
// layers 0..4 (gates + CNOT perm) + layer 5 shared RZ·RY·RZ gates (no perm).
__global__ __launch_bounds__(256) void qnn_shared_kernel(
    const float* __restrict__ P,      // (NL, NQ, 3)
    v2f* __restrict__ ws)             // out: 2048 amps, natural order
{
    __shared__ v2f lds[DIM];
    __shared__ v2f G[NL*NQ][4];
    const int t = threadIdx.x;        // 8 bits

    if (t < NL*NQ) {
        const float p0 = P[t*3+0], p1 = P[t*3+1], p2 = P[t*3+2];
        const float th = 0.5f*p1;
        const float c  = cosf(th), s = sinf(th);
        const float al = 0.5f*(p0+p2), be = 0.5f*(p0-p2);
        const float ca = cosf(al), sa = sinf(al);
        const float cb = cosf(be), sb = sinf(be);
        G[t][0] = (v2f){ c*ca, -c*sa};
        G[t][1] = (v2f){-s*cb, -s*sb};
        G[t][2] = (v2f){ s*cb, -s*sb};
        G[t][3] = (v2f){ c*ca,  c*sa};
    }

    // per-thread swizzled LDS bases
    const int a0w = swzA(t);                          // X1 write (k<<8)
    const int a1b = swzA(((t>>5)<<8) | (t&31));       // X1 read / X2 write (k<<5)
    const int a2b = swzA(((t>>2)<<5) | (t&3));        // X2 read / X3 write (k<<2)
    const int a3b = swzA(t ^ (t>>1));                 // X3 perm-gather read
    const int natb = ((t>>2)<<5) | (t&3);             // ws natural-order base

    v2f a[8];
    #pragma unroll
    for (int k = 0; k < 8; ++k) a[k] = (v2f){0.f, 0.f};
    if (t == 0) a[0] = (v2f){1.f, 0.f};
    __syncthreads();   // G ready

    #define CG(g_, rb_) { \
        const v2f U00=G[g_][0], U01=G[g_][1], U10=G[g_][2], U11=G[g_][3]; \
        _Pragma("unroll") \
        for (int kk = 0; kk < 8; ++kk) if (!(kk & (rb_))) { \
            const v2f a0 = a[kk], a1 = a[kk|(rb_)]; \
            a[kk]       = cmadd(U01, a1, cmadd(U00, a0, (v2f){0.f,0.f})); \
            a[kk|(rb_)] = cmadd(U11, a1, cmadd(U10, a0, (v2f){0.f,0.f})); \
        } }

    #define SG(g_, m_, b_) { \
        const v2f ca_ = (b_) ? G[g_][3] : G[g_][0]; \
        const v2f cb_ = (b_) ? G[g_][2] : G[g_][1]; \
        _Pragma("unroll") \
        for (int kk = 0; kk < 8; ++kk) { \
            v2f p; \
            p.x = __shfl_xor(a[kk].x, m_); \
            p.y = __shfl_xor(a[kk].y, m_); \
            a[kk] = cmadd(cb_, p, cmadd(ca_, a[kk], (v2f){0.f,0.f})); \
        } }

    for (int l = 0; l < NL; ++l) {
        const int g0 = l*NQ;
        CG(g0+0, 4) CG(g0+1, 2) CG(g0+2, 1)          // qubits 0,1,2 (bits 10,9,8)

        #pragma unroll
        for (int k = 0; k < 8; ++k) lds[a0w ^ swzA(k<<8)] = a[k];
        __syncthreads();
        #pragma unroll
        for (int k = 0; k < 8; ++k) a[k] = lds[a1b ^ swzA(k<<5)];
        __syncthreads();
        CG(g0+3, 4) CG(g0+4, 2) CG(g0+5, 1)          // qubits 3,4,5 (bits 7,6,5)

        #pragma unroll
        for (int k = 0; k < 8; ++k) lds[a1b ^ swzA(k<<5)] = a[k];
        __syncthreads();
        #pragma unroll
        for (int k = 0; k < 8; ++k) a[k] = lds[a2b ^ swzA(k<<2)];
        __syncthreads();
        CG(g0+6, 4) CG(g0+7, 2) CG(g0+8, 1)          // qubits 6,7,8 (bits 4,3,2)

        SG(g0+9, 2, (t>>1)&1)                        // qubit 9 (bit 1)
        SG(g0+10, 1, t&1)                            // qubit 10 (bit 0)

        if (l < NL-1) {
            #pragma unroll
            for (int k = 0; k < 8; ++k) lds[a2b ^ swzA(k<<2)] = a[k];
            __syncthreads();
            #pragma unroll
            for (int k = 0; k < 8; ++k)
                a[k] = lds[a3b ^ swzA((k<<8) ^ (k<<7))];   // src = g((k<<8)|t)
            __syncthreads();
        } else {
            #pragma unroll
            for (int k = 0; k < 8; ++k) ws[natb | (k<<2)] = a[k];
        }
    }
    #undef CG
    #undef SG
}

// ========= kernel 2: per-sample 11 real RY gates + CNOT perm, 8192 blocks ====
// 256 threads x 8 amps -> 8 blocks/CU x 4 waves = 32 waves/CU (100% occupancy).
__global__ __launch_bounds__(256, 8) void qnn_last_kernel(
    const float* __restrict__ X,      // (B, NQ)
    const v2f* __restrict__ S5,       // shared state, natural order
    v2f* __restrict__ out)            // (B, DIM)
{
    __shared__ v2f lds[DIM];
    __shared__ v2f gc[NQ];
    const int b = blockIdx.x;
    const int t = threadIdx.x;        // 8 bits

    if (t < NQ) {
        const float tx = 0.5f * X[(size_t)b*NQ + t];
        gc[t] = (v2f){cosf(tx), sinf(tx)};
    }

    // per-thread swizzled LDS bases (same layouts as kernel 1)
    const int a0w = swzA(t);
    const int a1b = swzA(((t>>5)<<8) | (t&31));
    const int a2b = swzA(((t>>2)<<5) | (t&3));
    const int a3b = swzA(t ^ (t>>1));

    // L0: reg k holds amp i = (k<<8)|t  (bits 10..8 local)
    v2f a[8];
    #pragma unroll
    for (int k = 0; k < 8; ++k) a[k] = S5[(k<<8) | t];
    __syncthreads();   // gc ready

    // real RY on reg bit rb: packed (re,im) -> v_pk_fma_f32
    #define RG(q_, rb_) { \
        const float c = gc[q_].x, s = gc[q_].y; \
        _Pragma("unroll") \
        for (int kk = 0; kk < 8; ++kk) if (!(kk & (rb_))) { \
            const v2f a0 = a[kk], a1 = a[kk|(rb_)]; \
            a[kk]       = c*a0 - s*a1; \
            a[kk|(rb_)] = s*a0 + c*a1; \
        } }

    // real RY on lane bit (mask m_): new = c*self + (bit? s : -s)*partner
    #define LG(q_, m_, bit_) { \
        const float c = gc[q_].x, s = gc[q_].y; \
        const float sg = (bit_) ? s : -s; \
        _Pragma("unroll") \
        for (int kk = 0; kk < 8; ++kk) { \
            v2f p; \
            p.x = __shfl_xor(a[kk].x, m_); \
            p.y = __shfl_xor(a[kk].y, m_); \
            a[kk] = c*a[kk] + sg*p; \
        } }

    RG(0, 4) RG(1, 2) RG(2, 1)                       // qubits 0,1,2 (bits 10,9,8)

    // X1 -> L1
    #pragma unroll
    for (int k = 0; k < 8; ++k) lds[a0w ^ swzA(k<<8)] = a[k];
    __syncthreads();
    #pragma unroll
    for (int k = 0; k < 8; ++k) a[k] = lds[a1b ^ swzA(k<<5)];
    __syncthreads();
    RG(3, 4) RG(4, 2) RG(5, 1)                       // qubits 3,4,5 (bits 7,6,5)

    // X2 -> L2
    #pragma unroll
    for (int k = 0; k < 8; ++k) lds[a1b ^ swzA(k<<5)] = a[k];
    __syncthreads();
    #pragma unroll
    for (int k = 0; k < 8; ++k) a[k] = lds[a2b ^ swzA(k<<2)];
    __syncthreads();
    RG(6, 4) RG(7, 2) RG(8, 1)                       // qubits 6,7,8 (bits 4,3,2)

    LG(9, 2, (t>>1)&1)                               // qubit 9 (bit 1, lane)
    LG(10, 1, t&1)                                   // qubit 10 (bit 0, lane)

    // X3: CNOT perm + relocalize to lane-major store layout o=(k<<8)|t
    #pragma unroll
    for (int k = 0; k < 8; ++k) lds[a2b ^ swzA(k<<2)] = a[k];
    __syncthreads();
    v2f* o = out + (size_t)b * DIM + t;
    #pragma unroll
    for (int k = 0; k < 8; ++k)
        o[k<<8] = lds[a3b ^ swzA((k<<8) ^ (k<<7))];  // src = g((k<<8)|t); 2KB/wave
    #undef RG
    #undef LG
}

extern "C" void kernel_launch(void* const* d_in, const int* in_sizes, int n_in,
                              void* d_out, int out_size, void* d_ws, size_t ws_size,
                              hipStream_t stream) {
    const float* X = (const float*)d_in[0];   // (B, NQ) float32
    const float* P = (const float*)d_in[1];   // (NL, NQ, 3) float32
    v2f* out = (v2f*)d_out;
    v2f* ws  = (v2f*)d_ws;                    // 16 KB shared state
    const int B = in_sizes[0] / NQ;           // 8192
    qnn_shared_kernel<<<1, 256, 0, stream>>>(P, ws);
    qnn_last_kernel<<<B, 256, 0, stream>>>(X, ws, out);
}